// Round 3
// baseline (282.584 us; speedup 1.0000x reference)
//
#include <hip/hip_runtime.h>

// H2G2: 2-layer RGCN (R=4, per-relation mean) + mean-pool + linear.
// R10: register-resident fused layer (231us total, layer 47us). R11 FAILED:
//   launch_bounds(256,4) VGPR cap -> scratch spill (WRITE 432MB, layer 221us).
// R12: channel-split wave pair, merged one-hot edge loop, 8KB LDS exchange:
//   layer STILL 47.0us (== R10) despite VALU 15->25%, occ 23->28.5%.
//   Invariant: FETCH_SIZE 52MB = 8 XCD x 6.4MB = full per-XCD L2 replication
//   of Xb/H (random src gather). 52MB/47us = 1.1 TB/s of random 64B fills
//   ~= 1 line/cy/XCD -> layer is L2-FILL-BOUND. Stop tuning the gather.
// R13: attack the ~135us preprocessing instead. bin+csr (2-level sort,
//   196 blocks, tmp round-trip, binary searches) replaced by direct CSR:
//   count((dst,rel) global atomics) -> 3-kernel exclusive scan (4N=200k)
//   -> atomic placement. Segment-internal edge order is irrelevant (sum).
//   inv[] deleted (layer derives counts from rpflat diffs + rcp). tmp deleted.

#define RR 4
#define HH 64
#define KK 320         // (RR+1)*HH
#define LWN (HH * KK)  // weights per layer = 20480

using frag_ab = __attribute__((ext_vector_type(8))) short;
using frag_cd = __attribute__((ext_vector_type(4))) float;

__device__ inline short f2bf(float f) {
    unsigned u = __builtin_bit_cast(unsigned, f);
    unsigned r = u + 0x7fffu + ((u >> 16) & 1u);  // RNE
    return (short)(r >> 16);
}
__device__ inline float bf2f(short s) {
    unsigned u = ((unsigned)(unsigned short)s) << 16;
    return __builtin_bit_cast(float, u);
}

// ---- prep: fused init-independent work, partitioned by blockIdx ----
// sections: [0,ecb) edge (dst,rel) count atomics | [ecb,+wbl) weights |
//           [+nb) gstart | rest: x fp32->bf16
__global__ __launch_bounds__(256) void prep_kernel(
    const int* __restrict__ dst, const int* __restrict__ et, int E,
    int* __restrict__ cnt,
    const float* __restrict__ basis1, const float* __restrict__ comp1, const float* __restrict__ root1,
    const float* __restrict__ basis2, const float* __restrict__ comp2, const float* __restrict__ root2,
    short* __restrict__ W1t, short* __restrict__ W2t,
    const int* __restrict__ batch, int* __restrict__ gstart, int N, int G,
    const float* __restrict__ x, short* __restrict__ Xb,
    int ecb, int wbl, int nb) {
    const int bid = blockIdx.x;
    const int t = threadIdx.x;
    if (bid < ecb) {  // ---- (dst,rel) histogram via global atomics ----
        int i = (bid * 256 + t) * 4;
        if (i + 3 < E) {
            int4 d4 = *(const int4*)&dst[i];
            int4 r4 = *(const int4*)&et[i];
            atomicAdd(&cnt[d4.x * 4 + r4.x], 1);
            atomicAdd(&cnt[d4.y * 4 + r4.y], 1);
            atomicAdd(&cnt[d4.z * 4 + r4.z], 1);
            atomicAdd(&cnt[d4.w * 4 + r4.w], 1);
        } else {
            for (int k = i; k < E; ++k) atomicAdd(&cnt[dst[k] * 4 + et[k]], 1);
        }
    } else if (bid < ecb + wbl) {  // ---- weights: Wt[c*320+k] = Wstack[k][c] ----
        int w = (bid - ecb) * 256 + t;
        int layer = w / LWN;
        int rem = w - layer * LWN;
        int c = rem / KK;
        int k = rem - c * KK;
        const float* basis = layer ? basis2 : basis1;
        const float* comp  = layer ? comp2  : comp1;
        const float* root  = layer ? root2  : root1;
        short* Wt          = layer ? W2t    : W1t;
        float v;
        if (k < HH) {
            v = root[k * HH + c];
        } else {
            int r = (k >> 6) - 1, kk = k & 63;
            v = 0.f;
#pragma unroll
            for (int b = 0; b < RR; ++b) v += comp[r * RR + b] * basis[(b * HH + kk) * HH + c];
        }
        Wt[c * KK + k] = f2bf(v);
    } else if (bid < ecb + wbl + nb) {  // ---- gstart ----
        int i = (bid - ecb - wbl) * 256 + t;
        if (i < N) {
            int b1 = batch[i];
            int b0 = (i == 0) ? -1 : batch[i - 1];
            for (int g = b0 + 1; g <= b1; ++g) gstart[g] = i;
            if (i == N - 1)
                for (int g = b1 + 1; g <= G; ++g) gstart[g] = N;
        }
    } else {  // ---- convert x fp32 -> bf16 ----
        int i4 = (bid - ecb - wbl - nb) * 256 + t;
        int base = i4 * 4;
        if (base < N * 64) {
            float4 f = *(const float4*)&x[base];
            short4 s;
            s.x = f2bf(f.x); s.y = f2bf(f.y); s.z = f2bf(f.z); s.w = f2bf(f.w);
            *(short4*)&Xb[base] = s;
        }
    }
}

// ---- scan1: per-block (1024 elems) exclusive scan of cnt, in place ----
__global__ __launch_bounds__(256) void scan1_kernel(int* __restrict__ cnt,
                                                    int* __restrict__ bsum, int n4) {
    __shared__ int ss[256];
    const int t = threadIdx.x;
    const int i = blockIdx.x * 1024 + t * 4;
    int4 c = make_int4(0, 0, 0, 0);
    if (i + 3 < n4) c = *(const int4*)&cnt[i];
    int s = c.x + c.y + c.z + c.w;
    ss[t] = s;
    __syncthreads();
#pragma unroll
    for (int off = 1; off < 256; off <<= 1) {
        int u = (t >= off) ? ss[t - off] : 0;
        __syncthreads();
        ss[t] += u;
        __syncthreads();
    }
    int excl = ss[t] - s;
    if (t == 255) bsum[blockIdx.x] = ss[255];
    if (i + 3 < n4) {
        int4 o;
        o.x = excl;
        o.y = excl + c.x;
        o.z = excl + c.x + c.y;
        o.w = excl + c.x + c.y + c.z;
        *(int4*)&cnt[i] = o;
    }
}

// ---- scan2: exclusive scan of block sums (nb <= 256), in place ----
__global__ __launch_bounds__(256) void scan2_kernel(int* __restrict__ bsum, int nb) {
    __shared__ int ss[256];
    const int t = threadIdx.x;
    int v = (t < nb) ? bsum[t] : 0;
    ss[t] = v;
    __syncthreads();
#pragma unroll
    for (int off = 1; off < 256; off <<= 1) {
        int u = (t >= off) ? ss[t - off] : 0;
        __syncthreads();
        ss[t] += u;
        __syncthreads();
    }
    if (t < nb) bsum[t] = ss[t] - v;
}

// ---- scan3: add block base; cnt becomes cursors, rpflat the CSR starts ----
__global__ __launch_bounds__(256) void scan3_kernel(int* __restrict__ cnt,
                                                    const int* __restrict__ bsum,
                                                    int* __restrict__ rpflat,
                                                    int n4, int E) {
    const int t = threadIdx.x;
    const int i = blockIdx.x * 1024 + t * 4;
    if (i + 3 < n4) {
        int base = bsum[blockIdx.x];
        int4 v = *(const int4*)&cnt[i];
        v.x += base; v.y += base; v.z += base; v.w += base;
        *(int4*)&cnt[i] = v;      // cursors for placement
        *(int4*)&rpflat[i] = v;   // CSR starts for layer
    }
    if (blockIdx.x == 0 && t == 0) rpflat[n4] = E;  // sentinel
}

// ---- place: scatter edges into (dst,rel) CSR segments ----
__global__ __launch_bounds__(256) void place_kernel(const int* __restrict__ src,
                                                    const int* __restrict__ dst,
                                                    const int* __restrict__ et,
                                                    int* __restrict__ cur,
                                                    int* __restrict__ eidx, int E) {
    const int i = (blockIdx.x * 256 + threadIdx.x) * 4;
    if (i + 3 < E) {
        int4 s4 = *(const int4*)&src[i];
        int4 d4 = *(const int4*)&dst[i];
        int4 r4 = *(const int4*)&et[i];
        int p0 = atomicAdd(&cur[d4.x * 4 + r4.x], 1);
        int p1 = atomicAdd(&cur[d4.y * 4 + r4.y], 1);
        int p2 = atomicAdd(&cur[d4.z * 4 + r4.z], 1);
        int p3 = atomicAdd(&cur[d4.w * 4 + r4.w], 1);
        eidx[p0] = (s4.x << 2) | r4.x;
        eidx[p1] = (s4.y << 2) | r4.y;
        eidx[p2] = (s4.z << 2) | r4.z;
        eidx[p3] = (s4.w << 2) | r4.w;
    } else {
        for (int k = i; k < E; ++k) {
            int p = atomicAdd(&cur[dst[k] * 4 + et[k]], 1);
            eidx[p] = (src[k] << 2) | et[k];
        }
    }
}

// ---- fused layer (R12 structure): 32 nodes/block; wave pair splits CHANNELS.
// ws=0 gathers low 8ch of its quad, ws=1 the high 8ch; both walk the full
// edge list (merged, one-hot accumulate, 4 edges in flight). ws=1 scales to
// bf16 and drops its 4 A-frags in 8KB LDS; ws=0 consumes directly in MFMA.
// Per-rel counts derived from rpflat diffs (inv[] deleted). ----
__global__ __launch_bounds__(256) void layer_kernel(
    const int* __restrict__ rpflat,
    const int* __restrict__ eidx,
    const short* __restrict__ Xb,
    const short* __restrict__ Wt,
    const float* __restrict__ bias,
    short* __restrict__ out, int n) {
    __shared__ short xpack[2][64][32];  // [pair][lane][4 frags x 8 bf16] = 8KB
    const int t = threadIdx.x;
    const int wv = t >> 6;
    const int pair = wv >> 1;   // which 16-node group
    const int ws = wv & 1;      // channel half: 0 = quad*8, 1 = 32+quad*8
    const int l = t & 63;
    const int m = l & 15;
    const int quad = l >> 4;
    const int node = blockIdx.x * 32 + pair * 16 + m;
    const bool valid = node < n;

    float acc[4][8];  // [rel][8 ch of this lane's half]
#pragma unroll
    for (int r = 0; r < 4; ++r)
#pragma unroll
        for (int j = 0; j < 8; ++j) acc[r][j] = 0.f;

    int k0 = 0, k1 = 0;
    float4 iv = make_float4(0.f, 0.f, 0.f, 0.f);
    if (valid) {
        int4 r4 = *(const int4*)&rpflat[node * 4];
        int kend = rpflat[node * 4 + 4];
        k0 = r4.x;
        k1 = kend;
        iv.x = 1.0f / fmaxf((float)(r4.y - r4.x), 1.0f);
        iv.y = 1.0f / fmaxf((float)(r4.z - r4.y), 1.0f);
        iv.z = 1.0f / fmaxf((float)(r4.w - r4.z), 1.0f);
        iv.w = 1.0f / fmaxf((float)(kend - r4.w), 1.0f);
    }
    const short* xbq = Xb + ws * 32 + quad * 8;

#define ACC(P, F)                                                             \
    {                                                                         \
        int r_ = (P) & 3;                                                     \
        float s0_ = (r_ == 0) ? 1.f : 0.f;                                    \
        float s1_ = (r_ == 1) ? 1.f : 0.f;                                    \
        float s2_ = (r_ == 2) ? 1.f : 0.f;                                    \
        float s3_ = (r_ == 3) ? 1.f : 0.f;                                    \
        _Pragma("unroll") for (int j = 0; j < 8; ++j) {                       \
            float v_ = bf2f((F)[j]);                                          \
            acc[0][j] += v_ * s0_;                                            \
            acc[1][j] += v_ * s1_;                                            \
            acc[2][j] += v_ * s2_;                                            \
            acc[3][j] += v_ * s3_;                                            \
        }                                                                     \
    }

    int k = k0;
    for (; k + 3 < k1; k += 4) {  // 4 edges in flight
        int p0 = eidx[k];
        int p1 = eidx[k + 1];
        int p2 = eidx[k + 2];
        int p3 = eidx[k + 3];
        const short* a0p = xbq + (size_t)(p0 >> 2) * 64;
        const short* a1p = xbq + (size_t)(p1 >> 2) * 64;
        const short* a2p = xbq + (size_t)(p2 >> 2) * 64;
        const short* a3p = xbq + (size_t)(p3 >> 2) * 64;
        frag_ab f0 = *(const frag_ab*)a0p;
        frag_ab f1 = *(const frag_ab*)a1p;
        frag_ab f2 = *(const frag_ab*)a2p;
        frag_ab f3 = *(const frag_ab*)a3p;
        ACC(p0, f0)
        ACC(p1, f1)
        ACC(p2, f2)
        ACC(p3, f3)
    }
    for (; k < k1; ++k) {  // remainder (<=3 edges)
        int p0 = eidx[k];
        const short* a0p = xbq + (size_t)(p0 >> 2) * 64;
        frag_ab f0 = *(const frag_ab*)a0p;
        ACC(p0, f0)
    }
#undef ACC

    // scale by per-relation inv-degree, pack to bf16 A-frag halves
    frag_ab y[4];
    {
        float s0 = iv.x, s1 = iv.y, s2 = iv.z, s3 = iv.w;
#pragma unroll
        for (int j = 0; j < 8; ++j) {
            y[0][j] = f2bf(acc[0][j] * s0);
            y[1][j] = f2bf(acc[1][j] * s1);
            y[2][j] = f2bf(acc[2][j] * s2);
            y[3][j] = f2bf(acc[3][j] * s3);
        }
    }

    // exchange: ws=1 deposits its 4 high-half frags; ws=0 consumes.
    if (ws == 1) {
#pragma unroll
        for (int r = 0; r < 4; ++r)
            *(frag_ab*)&xpack[pair][l][r * 8] = y[r];
    }
    __syncthreads();
    if (ws == 1) return;

    // build A-frags: a[0..1] = X row; a[2+2r] = own (low), a[3+2r] = LDS (high)
    frag_ab a[10];
    a[0] = frag_ab{};
    a[1] = frag_ab{};
    if (valid) {
        const short* xr = Xb + (size_t)node * 64 + quad * 8;
        a[0] = *(const frag_ab*)xr;
        a[1] = *(const frag_ab*)(xr + 32);
    }
#pragma unroll
    for (int r = 0; r < 4; ++r) {
        a[2 + 2 * r] = y[r];
        a[3 + 2 * r] = *(const frag_ab*)&xpack[pair][l][r * 8];
    }

    const int nrow_base = blockIdx.x * 32 + pair * 16 + quad * 4;
#pragma unroll
    for (int ct = 0; ct < 4; ++ct) {
        const short* bp = Wt + (size_t)(ct * 16 + m) * KK + quad * 8;
        frag_cd c = {0.f, 0.f, 0.f, 0.f};
#pragma unroll
        for (int f = 0; f < 10; ++f) {
            frag_ab bf = *(const frag_ab*)(bp + f * 32);
            c = __builtin_amdgcn_mfma_f32_16x16x32_bf16(a[f], bf, c, 0, 0, 0);
        }
        int col = ct * 16 + m;
        float bv = bias[col];
#pragma unroll
        for (int r = 0; r < 4; ++r) {
            int nr = nrow_base + r;
            if (nr < n) out[(size_t)nr * 64 + col] = f2bf(fmaxf(c[r] + bv, 0.f));
        }
    }
}

// ---- pool (segmented) + classifier ----
__global__ __launch_bounds__(256) void pool_cls_kernel(const short* __restrict__ h2,
                                                       const int* __restrict__ gstart,
                                                       const float* __restrict__ w,
                                                       const float* __restrict__ b,
                                                       float* __restrict__ out) {
    __shared__ float red[4][64];
    const int g = blockIdx.x;
    const int t = threadIdx.x;
    const int h = t & 63;
    const int wv = t >> 6;
    const int s = gstart[g], e = gstart[g + 1];

    float acc = 0.f;
    for (int i = s + wv; i < e; i += 4) acc += bf2f(h2[(size_t)i * 64 + h]);
    red[wv][h] = acc;
    __syncthreads();
    if (wv == 0) {
        float sum = red[0][h] + red[1][h] + red[2][h] + red[3][h];
        red[0][h] = sum / fmaxf((float)(e - s), 1.0f);
    }
    __syncthreads();
    if (t < 4) {
        float sres = 0.f;
#pragma unroll 8
        for (int hh = 0; hh < 64; ++hh) sres += red[0][hh] * w[hh * 4 + t];
        out[g * 4 + t] = sres + b[t];
    }
}

extern "C" void kernel_launch(void* const* d_in, const int* in_sizes, int n_in,
                              void* d_out, int out_size, void* d_ws, size_t ws_size,
                              hipStream_t stream) {
    const float* x        = (const float*)d_in[0];
    const int* edge_index = (const int*)d_in[1];
    const int* edge_type  = (const int*)d_in[2];
    const int* batch      = (const int*)d_in[3];
    const float* basis1 = (const float*)d_in[4];
    const float* comp1  = (const float*)d_in[5];
    const float* root1  = (const float*)d_in[6];
    const float* bias1  = (const float*)d_in[7];
    const float* basis2 = (const float*)d_in[8];
    const float* comp2  = (const float*)d_in[9];
    const float* root2  = (const float*)d_in[10];
    const float* bias2  = (const float*)d_in[11];
    const float* clas_w = (const float*)d_in[12];
    const float* clas_b = (const float*)d_in[13];

    const int N = in_sizes[0] / 64;
    const int E = in_sizes[2];
    const int G = out_size / 4;
    const int* src = edge_index;
    const int* dst = edge_index + E;
    const int N4 = N * 4;

    char* base = (char*)d_ws;
    size_t off = 0;
    auto carve = [&](size_t bytes) { void* p = base + off; off = (off + bytes + 15) & ~(size_t)15; return p; };
    int*   cnt     = (int*)carve(sizeof(int) * (size_t)N4);        // counts -> cursors
    int*   bsum    = (int*)carve(sizeof(int) * 256);
    int*   rpflat  = (int*)carve(sizeof(int) * ((size_t)N4 + 4));  // CSR starts + sentinel
    int*   gstart  = (int*)carve(sizeof(int) * ((size_t)G + 1));
    int*   eidx    = (int*)carve(sizeof(int) * (size_t)E);
    short* W1t     = (short*)carve(sizeof(short) * LWN);
    short* W2t     = (short*)carve(sizeof(short) * LWN);
    short* Xb1     = (short*)carve(sizeof(short) * (size_t)N * 64);
    short* H1      = (short*)carve(sizeof(short) * (size_t)N * 64);
    short* H2      = (short*)carve(sizeof(short) * (size_t)N * 64);

    const int nb  = (N + 255) / 256;
    const int ecb = (E + 1023) / 1024;
    const int wbl = (2 * LWN + 255) / 256;
    const int cvb = (N * 64 / 4 + 255) / 256;
    const int prep_blocks = ecb + wbl + nb + cvb;
    const int snb = (N4 + 1023) / 1024;  // scan blocks (<=256 for N<=65536)

    hipMemsetAsync(cnt, 0, sizeof(int) * (size_t)N4, stream);

    prep_kernel<<<prep_blocks, 256, 0, stream>>>(
        dst, edge_type, E, cnt,
        basis1, comp1, root1, basis2, comp2, root2, W1t, W2t,
        batch, gstart, N, G, x, Xb1, ecb, wbl, nb);
    scan1_kernel<<<snb, 256, 0, stream>>>(cnt, bsum, N4);
    scan2_kernel<<<1, 256, 0, stream>>>(bsum, snb);
    scan3_kernel<<<snb, 256, 0, stream>>>(cnt, bsum, rpflat, N4, E);
    place_kernel<<<ecb, 256, 0, stream>>>(src, dst, edge_type, cnt, eidx, E);

    const int layer_blocks = (N + 31) / 32;

    layer_kernel<<<layer_blocks, 256, 0, stream>>>(rpflat, eidx, Xb1, W1t, bias1, H1, N);
    layer_kernel<<<layer_blocks, 256, 0, stream>>>(rpflat, eidx, H1, W2t, bias2, H2, N);

    pool_cls_kernel<<<G, 256, 0, stream>>>(H2, gstart, clas_w, clas_b, (float*)d_out);
}